// Round 12
// baseline (198.648 us; speedup 1.0000x reference)
//
#include <hip/hip_runtime.h>

#define HID 1024
#define HEADS 16
#define HD 64
#define TAB 129
#define QSTR 136   // padded qtab row stride (ushorts, 16B-aligned rows)
#define BATCH 8
#define SEQ 512

typedef unsigned int uint;
typedef unsigned short ushort;
typedef unsigned char uchar;
typedef __attribute__((ext_vector_type(4))) float f32x4;
typedef __attribute__((ext_vector_type(8))) __bf16 bf16x8;

// ---------------------------------------------------------------------------
// bf16 helpers
// ---------------------------------------------------------------------------
__device__ __forceinline__ ushort f2b(float x) {
    uint b = __float_as_uint(x);
    uint r = (b + 0x7fffu + ((b >> 16) & 1u)) >> 16;
    return (ushort)r;
}
__device__ __forceinline__ uint pk(float lo, float hi) {
    return (uint)f2b(lo) | ((uint)f2b(hi) << 16);
}
__device__ __forceinline__ float b2f(ushort u) {
    return __uint_as_float(((uint)u) << 16);
}
union U16x8 { uint u[4]; bf16x8 v; ushort s[8]; uint4 q; };
__device__ __forceinline__ bf16x8 pack8(float a0, float a1, float a2, float a3,
                                        float a4, float a5, float a6, float a7) {
    U16x8 r;
    r.u[0] = pk(a0, a1); r.u[1] = pk(a2, a3);
    r.u[2] = pk(a4, a5); r.u[3] = pk(a6, a7);
    return r.v;
}

// materialization fence: forces the value to be resident in VGPRs here,
// preventing the compiler from sinking its producing load to the use site.
__device__ __forceinline__ void keep(bf16x8& v) {
    uint4* u = (uint4*)&v;
    asm volatile("" : "+v"(u->x), "+v"(u->y), "+v"(u->z), "+v"(u->w));
}
__device__ __forceinline__ void keepu(uint& v) {
    asm volatile("" : "+v"(v));
}

#define GL16(gp, lp) __builtin_amdgcn_global_load_lds( \
    (const __attribute__((address_space(1))) void*)(gp), \
    (__attribute__((address_space(3))) void*)(lp), 16, 0, 0)

// LDS-only barrier: order DS ops, keep in-flight VMEM alive
#define LDS_BARRIER() do { \
        asm volatile("s_waitcnt lgkmcnt(0)" ::: "memory"); \
        __builtin_amdgcn_s_barrier(); \
    } while (0)

// ---------------------------------------------------------------------------
// convert fp32 -> bf16
// ---------------------------------------------------------------------------
struct ConvArgs { const float* src[7]; ushort* dst[7]; };

__global__ __launch_bounds__(256) void convert_bf16(ConvArgs ca) {
    int bid = blockIdx.x;
    int ti, lb;
    if (bid < 6144) { ti = bid >> 11; lb = bid & 2047; }
    else { int r = bid - 6144; ti = 3 + (r >> 9); lb = r & 511; }
    const float* s = ca.src[ti] + (size_t)lb * 2048 + (threadIdx.x << 3);
    ushort*      d = ca.dst[ti] + (size_t)lb * 2048 + (threadIdx.x << 3);
    float4 a = *(const float4*)s;
    float4 c = *(const float4*)(s + 4);
    uint4 u;
    u.x = pk(a.x, a.y); u.y = pk(a.z, a.w);
    u.z = pk(c.x, c.y); u.w = pk(c.z, c.w);
    *(uint4*)d = u;
}

// ---------------------------------------------------------------------------
// bf16 MFMA GEMM (QKV, unchanged): C_z = A_z @ W_z^T + bias_z
// ---------------------------------------------------------------------------
struct GemmArgs {
    const ushort* A[3];
    const ushort* W[3];
    const float*  bias[3];
    float*        Cf[3];
    ushort*       Cb[3];
};

__global__ __launch_bounds__(256) void gemm_bf16(GemmArgs ga, int M, int N, int K) {
    __shared__ ushort As[2][128 * 32];
    __shared__ ushort Bs[2][128 * 32];
    const int z = blockIdx.z;
    const ushort* A = ga.A[z];
    const ushort* W = ga.W[z];
    const int tid = threadIdx.x;
    const int m0 = blockIdx.y * 128;
    const int n0 = blockIdx.x * 128;

    const int w  = tid >> 6;
    const int l  = tid & 63;
    const int lr = l & 15;
    const int lg = l >> 4;
    const int wm = w >> 1;
    const int wn = w & 1;

    const int sr = tid >> 2;
    const int sc = tid & 3;
    const int g  = sc ^ ((sr >> 1) & 3);
    const ushort* Ag0 = A + (size_t)(m0 + sr)      * K + g * 8;
    const ushort* Ag1 = A + (size_t)(m0 + sr + 64) * K + g * 8;
    const ushort* Wg0 = W + (size_t)(n0 + sr)      * K + g * 8;
    const ushort* Wg1 = W + (size_t)(n0 + sr + 64) * K + g * 8;

    f32x4 acc[4][4];
#pragma unroll
    for (int mt = 0; mt < 4; ++mt)
#pragma unroll
        for (int nt = 0; nt < 4; ++nt) acc[mt][nt] = (f32x4){0.f, 0.f, 0.f, 0.f};

#define STAGE(buf, k0) do { \
        GL16(Ag0 + (k0), &As[buf][w * 512]); \
        GL16(Ag1 + (k0), &As[buf][2048 + w * 512]); \
        GL16(Wg0 + (k0), &Bs[buf][w * 512]); \
        GL16(Wg1 + (k0), &Bs[buf][2048 + w * 512]); \
    } while (0)

    const int swz = (lr >> 1) & 3;
#define COMPUTE(buf) do { \
        bf16x8 af[4], bf[4]; \
        _Pragma("unroll") \
        for (int mt = 0; mt < 4; ++mt) \
            af[mt] = *(const bf16x8*)&As[buf][(wm * 64 + mt * 16 + lr) * 32 + (lg ^ swz) * 8]; \
        _Pragma("unroll") \
        for (int nt = 0; nt < 4; ++nt) \
            bf[nt] = *(const bf16x8*)&Bs[buf][(wn * 64 + nt * 16 + lr) * 32 + (lg ^ swz) * 8]; \
        _Pragma("unroll") \
        for (int mt = 0; mt < 4; ++mt) \
            _Pragma("unroll") \
            for (int nt = 0; nt < 4; ++nt) \
                acc[mt][nt] = __builtin_amdgcn_mfma_f32_16x16x32_bf16(af[mt], bf[nt], acc[mt][nt], 0, 0, 0); \
    } while (0)

    STAGE(0, 0);
    __syncthreads();
    const int nk = K / 32;
    for (int t = 0; t < nk - 1; ++t) {
        STAGE((t + 1) & 1, (size_t)(t + 1) * 32);
        COMPUTE(t & 1);
        __syncthreads();
    }
    COMPUTE((nk - 1) & 1);

    const float* bias = ga.bias[z];
    float bv[4];
#pragma unroll
    for (int nt = 0; nt < 4; ++nt) bv[nt] = bias[n0 + wn * 64 + nt * 16 + lr];
    float*  Cf = ga.Cf[z];
    ushort* Cb = ga.Cb[z];
    if (Cf) {
#pragma unroll
        for (int mt = 0; mt < 4; ++mt)
#pragma unroll
            for (int r4 = 0; r4 < 4; ++r4) {
                size_t m = m0 + wm * 64 + mt * 16 + lg * 4 + r4;
                float* crow = Cf + m * N + n0 + wn * 64 + lr;
#pragma unroll
                for (int nt = 0; nt < 4; ++nt)
                    crow[nt * 16] = acc[mt][nt][r4] + bv[nt];
            }
    } else {
#pragma unroll
        for (int mt = 0; mt < 4; ++mt)
#pragma unroll
            for (int r4 = 0; r4 < 4; ++r4) {
                size_t m = m0 + wm * 64 + mt * 16 + lg * 4 + r4;
                ushort* crow = Cb + m * N + n0 + wn * 64 + lr;
#pragma unroll
                for (int nt = 0; nt < 4; ++nt)
                    crow[nt * 16] = f2b(acc[mt][nt][r4] + bv[nt]);
            }
    }
#undef STAGE
#undef COMPUTE
}

// ---------------------------------------------------------------------------
// Wo GEMM, BN=64 tile (unchanged R11)
// ---------------------------------------------------------------------------
__global__ __launch_bounds__(256) void gemm_wo(const ushort* __restrict__ A,
                                               const ushort* __restrict__ W,
                                               const float* __restrict__ bias,
                                               float* __restrict__ Cf) {
    const int M = BATCH * SEQ, N = HID, K = HID;
    __shared__ ushort As[2][128 * 32];
    __shared__ ushort Bs[2][64 * 32];
    const int tid = threadIdx.x;
    const int m0 = blockIdx.y * 128;
    const int n0 = blockIdx.x * 64;

    const int w  = tid >> 6;
    const int l  = tid & 63;
    const int lr = l & 15;
    const int lg = l >> 4;
    const int wm = w >> 1;
    const int wn = w & 1;

    const int sr = tid >> 2;
    const int sc = tid & 3;
    const int g  = sc ^ ((sr >> 1) & 3);
    const ushort* Ag0 = A + (size_t)(m0 + sr)      * K + g * 8;
    const ushort* Ag1 = A + (size_t)(m0 + sr + 64) * K + g * 8;
    const ushort* Wg0 = W + (size_t)(n0 + sr)      * K + g * 8;

    f32x4 acc[4][2];
#pragma unroll
    for (int mt = 0; mt < 4; ++mt)
#pragma unroll
        for (int nt = 0; nt < 2; ++nt) acc[mt][nt] = (f32x4){0.f, 0.f, 0.f, 0.f};

#define STAGE(buf, k0) do { \
        GL16(Ag0 + (k0), &As[buf][w * 512]); \
        GL16(Ag1 + (k0), &As[buf][2048 + w * 512]); \
        GL16(Wg0 + (k0), &Bs[buf][w * 512]); \
    } while (0)

    const int swz = (lr >> 1) & 3;
#define COMPUTE(buf) do { \
        bf16x8 af[4], bf[2]; \
        _Pragma("unroll") \
        for (int mt = 0; mt < 4; ++mt) \
            af[mt] = *(const bf16x8*)&As[buf][(wm * 64 + mt * 16 + lr) * 32 + (lg ^ swz) * 8]; \
        _Pragma("unroll") \
        for (int nt = 0; nt < 2; ++nt) \
            bf[nt] = *(const bf16x8*)&Bs[buf][(wn * 32 + nt * 16 + lr) * 32 + (lg ^ swz) * 8]; \
        _Pragma("unroll") \
        for (int mt = 0; mt < 4; ++mt) \
            _Pragma("unroll") \
            for (int nt = 0; nt < 2; ++nt) \
                acc[mt][nt] = __builtin_amdgcn_mfma_f32_16x16x32_bf16(af[mt], bf[nt], acc[mt][nt], 0, 0, 0); \
    } while (0)

    STAGE(0, 0);
    __syncthreads();
    const int nk = K / 32;
    for (int t = 0; t < nk - 1; ++t) {
        STAGE((t + 1) & 1, (size_t)(t + 1) * 32);
        COMPUTE(t & 1);
        __syncthreads();
    }
    COMPUTE((nk - 1) & 1);

    float bv[2];
#pragma unroll
    for (int nt = 0; nt < 2; ++nt) bv[nt] = bias[n0 + wn * 32 + nt * 16 + lr];
#pragma unroll
    for (int mt = 0; mt < 4; ++mt)
#pragma unroll
        for (int r4 = 0; r4 < 4; ++r4) {
            size_t m = m0 + wm * 64 + mt * 16 + lg * 4 + r4;
            float* crow = Cf + m * N + n0 + wn * 32 + lr;
#pragma unroll
            for (int nt = 0; nt < 2; ++nt)
                crow[nt * 16] = acc[mt][nt][r4] + bv[nt];
        }
#undef STAGE
#undef COMPUTE
}

// ---------------------------------------------------------------------------
// prep_kernel: fused qtab (MFMA) + V-transpose + tvT + fm int32->uint8.
//  blocks 0..255    : qtab via MFMA
//  blocks 256..767  : vT transpose
//  block  768       : tvT
//  blocks 769..1792 : fm8[i] = (uchar)fmat[i]   (2048 ints per block)
// ---------------------------------------------------------------------------
__global__ __launch_bounds__(256) void prep_kernel(const ushort* __restrict__ qb,
                                                   const float* __restrict__ table_k,
                                                   const ushort* __restrict__ vb,
                                                   const float* __restrict__ table_v,
                                                   const int* __restrict__ fmat,
                                                   ushort* __restrict__ qtab,
                                                   ushort* __restrict__ vT,
                                                   ushort* __restrict__ tvT,
                                                   uchar* __restrict__ fm8) {
    __shared__ __align__(16) ushort shmem[144 * 72];   // 20,736 B
    const int wg  = blockIdx.x;
    const int tid = threadIdx.x;

    if (wg < 256) {
        // ---- qtab via MFMA: A = table_k rows (t), B = q rows -> C[t][q] ----
        const int h    = wg & 15;
        const int half = (wg >> 4) & 1;
        const int b    = wg >> 5;
        const int q0   = half * 256;
        ushort* tk = shmem;
        for (int i = tid; i < TAB * 8; i += 256) {
            int row = i >> 3, gr = i & 7;
            const float* src = table_k + row * HD + gr * 8;
            float4 a = *(const float4*)src;
            float4 c = *(const float4*)(src + 4);
            uint4 u;
            u.x = pk(a.x, a.y); u.y = pk(a.z, a.w);
            u.z = pk(c.x, c.y); u.w = pk(c.z, c.w);
            *(uint4*)&tk[row * 72 + gr * 8] = u;
        }
        __syncthreads();

        const int w  = tid >> 6;
        const int l  = tid & 63;
        const int lr = l & 15;
        const int lg = l >> 4;
        bf16x8 qf[4][2];
#pragma unroll
        for (int qt = 0; qt < 4; ++qt) {
            const ushort* qrow = qb + ((size_t)(b * SEQ) + q0 + w * 64 + qt * 16 + lr) * HID + h * HD;
            qf[qt][0] = *(const bf16x8*)(qrow + lg * 8);
            qf[qt][1] = *(const bf16x8*)(qrow + 32 + lg * 8);
        }
        ushort* outbase = qtab + ((size_t)(b * HEADS + h) * SEQ + q0 + w * 64) * QSTR;
#pragma unroll
        for (int mt = 0; mt < 9; ++mt) {
            bf16x8 tf0 = *(const bf16x8*)&tk[(mt * 16 + lr) * 72 + lg * 8];
            bf16x8 tf1 = *(const bf16x8*)&tk[(mt * 16 + lr) * 72 + 32 + lg * 8];
#pragma unroll
            for (int qt = 0; qt < 4; ++qt) {
                f32x4 acc = (f32x4){0.f, 0.f, 0.f, 0.f};
                acc = __builtin_amdgcn_mfma_f32_16x16x32_bf16(tf0, qf[qt][0], acc, 0, 0, 0);
                acc = __builtin_amdgcn_mfma_f32_16x16x32_bf16(tf1, qf[qt][1], acc, 0, 0, 0);
                ushort* orow = outbase + (size_t)(qt * 16 + lr) * QSTR;
                if (mt < 8) {
                    uint2 pu;
                    pu.x = pk(acc[0], acc[1]); pu.y = pk(acc[2], acc[3]);
                    *(uint2*)&orow[mt * 16 + lg * 4] = pu;
                } else if (lg == 0) {
                    orow[128] = f2b(acc[0]);
                }
            }
        }
    } else if (wg < 768) {
        // ---- V transpose ----
        const int vw = wg - 256;
        ushort* tile = shmem;
        const int b = vw >> 6, h = (vw >> 2) & 15, kc = vw & 3;
        const int k0 = kc * 128;
        {
            const int kr = tid >> 1, dc = (tid & 1) * 32;
            const ushort* src = vb + ((size_t)(b * SEQ) + k0 + kr) * HID + h * 64 + dc;
#pragma unroll
            for (int j = 0; j < 4; ++j) {
                uint4 u = *(const uint4*)(src + j * 8);
                *(uint4*)&tile[kr * 72 + dc + j * 8] = u;
            }
        }
        __syncthreads();
        {
            const int dr = tid >> 2, kc2 = (tid & 3) * 32;
            ushort* dst = vT + ((size_t)(b * 16 + h) * 64 + dr) * 512 + k0 + kc2;
#pragma unroll
            for (int j = 0; j < 4; ++j) {
                U16x8 o;
#pragma unroll
                for (int i = 0; i < 8; ++i)
                    o.s[i] = tile[(kc2 + j * 8 + i) * 72 + dr];
                *(uint4*)(dst + j * 8) = o.q;
            }
        }
    } else if (wg == 768) {
        // ---- tvT ----
        const int tt = tid >> 1, dc = (tid & 1) * 32;
        const float* src = table_v + (size_t)tt * HD + dc;
#pragma unroll
        for (int i = 0; i < 32; ++i)
            tvT[(size_t)(dc + i) * 128 + tt] = f2b(src[i]);
    } else {
        // ---- fm int32 -> uint8 (values 0..128) ----
        const size_t base = (size_t)(wg - 769) * 2048 + (size_t)tid * 8;
        int4 a = *(const int4*)(fmat + base);
        int4 c = *(const int4*)(fmat + base + 4);
        uint lo = (uint)a.x | ((uint)a.y << 8) | ((uint)a.z << 16) | ((uint)a.w << 24);
        uint hi = (uint)c.x | ((uint)c.y << 8) | ((uint)c.z << 16) | ((uint)c.w << 24);
        uint2 o; o.x = lo; o.y = hi;
        *(uint2*)(fm8 + base) = o;
    }
}

// ---------------------------------------------------------------------------
// Fused attention v10: k-split 4 waves x 2 k-tiles; ds_add_u32 bins;
// batched K/fm loads with materialization fences (loads complete in one
// vmcnt window, then pure compute); same for V in PV; fm as uint8.
// ---------------------------------------------------------------------------
__global__ __launch_bounds__(256, 3) void attn_mfma(const ushort* __restrict__ qp,
                                                    const ushort* __restrict__ kp,
                                                    const ushort* __restrict__ vT,
                                                    const ushort* __restrict__ qt,
                                                    const uchar* __restrict__ fm8,
                                                    const float* __restrict__ table_v,
                                                    const ushort* __restrict__ tvT,
                                                    ushort* __restrict__ x) {
    constexpr float FIX = 65536.0f;
    constexpr float INV_FIX = 1.0f / 65536.0f;

    __shared__ __align__(16) ushort qtb[16 * QSTR];    //  4,352 B
    __shared__ __align__(16) uint   sbin[16 * 132];    //  8,448 B (fixed-point)
    __shared__ __align__(16) ushort P[4][16 * 136];    // 17,408 B (later: obuf f32)
    __shared__ float rowsumw[4][16];                   //    256 B

    const int tid = threadIdx.x;
    const int w   = tid >> 6;         // wave 0..3 -> k-tiles {2w, 2w+1}
    const int l   = tid & 63;
    const int lr  = l & 15;
    const int lg  = l >> 4;

    const int wg   = blockIdx.x;
    const int work = (wg & 7) * 512 + (wg >> 3);
    const int qblk = work & 31;
    const int h    = (work >> 5) & 15;
    const int b    = work >> 9;
    const int q0   = qblk * 16;
    const size_t bSEQ = (size_t)b * SEQ;
    const int hHD = h * HD;

    const uchar*  fmrow8   = fm8 + (bSEQ + q0 + lr) * SEQ;
    const ushort* kfr_base = kp + (bSEQ + lr) * HID + hHD;
    const ushort* vfr_base = vT + ((size_t)(b * HEADS + h) * HD + lr) * SEQ;

    bf16x8 qfrag[2];
    {
        const ushort* qrow = qp + (bSEQ + q0 + lr) * HID + hHD;
        qfrag[0] = *(const bf16x8*)(qrow + lg * 8);
        qfrag[1] = *(const bf16x8*)(qrow + 32 + lg * 8);
    }

    // ---- prologue: stage qtab rows, zero bins ----
    {
        const uint4* src = (const uint4*)(qt + ((size_t)(b * HEADS + h) * SEQ + q0) * QSTR);
        uint4* dst = (uint4*)qtb;
        for (int i = tid; i < 16 * QSTR / 8; i += 256) dst[i] = src[i];
    }
    {
        uint4 z = {0u, 0u, 0u, 0u};
        uint4* dz = (uint4*)sbin;
        for (int i = tid; i < 16 * 132 / 4; i += 256) dz[i] = z;
    }
    LDS_BARRIER();                                     // sync1

    // ---- Phase 1a: batched K/fm loads + fence, then pure MFMA stream ----
    bf16x8 kfr[8][2];
    uint   fmu[8];
#pragma unroll
    for (int i = 0; i < 8; ++i) {
        const int t  = i >> 2;
        const int mt = i & 3;
        const int k0 = (w * 2 + t) * 64;
        const ushort* kr = kfr_base + (size_t)(k0 + mt * 16) * HID;
        kfr[i][0] = *(const bf16x8*)(kr + lg * 8);
        kfr[i][1] = *(const bf16x8*)(kr + 32 + lg * 8);
        fmu[i] = *(const uint*)(fmrow8 + k0 + mt * 16 + lg * 4);
    }
#pragma unroll
    for (int i = 0; i < 8; ++i) { keep(kfr[i][0]); keep(kfr[i][1]); keepu(fmu[i]); }

    f32x4 stv[8];
#pragma unroll
    for (int i = 0; i < 8; ++i) {
        f32x4 st = (f32x4){0.f, 0.f, 0.f, 0.f};
        st = __builtin_amdgcn_mfma_f32_16x16x32_bf16(kfr[i][0], qfrag[0], st, 0, 0, 0);
        st = __builtin_amdgcn_mfma_f32_16x16x32_bf16(kfr[i][1], qfrag[1], st, 0, 0, 0);
        stv[i] = st;
    }

    // ---- Phase 1b: gather + exp + bins (u32 fixed-point) + P ----
    float lsum = 0.f;
#pragma unroll
    for (int i = 0; i < 8; ++i) {
        const int t  = i >> 2;
        const int mt = i & 3;
        const uint fm = fmu[i];
        const int t0 = fm & 255, t1 = (fm >> 8) & 255, t2 = (fm >> 16) & 255, t3 = fm >> 24;
        const f32x4 st = stv[i];
        float pr0 = __expf((st[0] + b2f(qtb[lr * QSTR + t0])) * 0.125f);
        float pr1 = __expf((st[1] + b2f(qtb[lr * QSTR + t1])) * 0.125f);
        float pr2 = __expf((st[2] + b2f(qtb[lr * QSTR + t2])) * 0.125f);
        float pr3 = __expf((st[3] + b2f(qtb[lr * QSTR + t3])) * 0.125f);
        lsum += pr0 + pr1 + pr2 + pr3;
        __hip_atomic_fetch_add(&sbin[lr * 132 + t0], (uint)(pr0 * FIX),
                               __ATOMIC_RELAXED, __HIP_MEMORY_SCOPE_WORKGROUP);
        __hip_atomic_fetch_add(&sbin[lr * 132 + t1], (uint)(pr1 * FIX),
                               __ATOMIC_RELAXED, __HIP_MEMORY_SCOPE_WORKGROUP);
        __hip_atomic_fetch_add(&sbin[lr * 132 + t2], (uint)(pr2 * FIX),
                               __ATOMIC_RELAXED, __HIP_MEMORY_SCOPE_WORKGROUP);
        __hip_atomic_fetch_add(&sbin[lr * 132 + t3], (uint)(pr3 * FIX),
                               __ATOMIC_RELAXED, __HIP_MEMORY_SCOPE_WORKGROUP);
        uint2 pu;
        pu.x = pk(pr0, pr1); pu.y = pk(pr2, pr3);
        *(uint2*)&P[w][lr * 136 + t * 64 + mt * 16 + lg * 4] = pu;
    }
    lsum += __shfl_xor(lsum, 16);
    lsum += __shfl_xor(lsum, 32);
    if (lg == 0) rowsumw[w][lr] = lsum;

    // ---- PV: batched V loads + fence, then P readback + MFMA ----
    bf16x8 vfr[2][4][2];
#pragma unroll
    for (int t = 0; t < 2; ++t) {
        const int k0 = (w * 2 + t) * 64;
#pragma unroll
        for (int nt = 0; nt < 4; ++nt) {
            const ushort* vr = vfr_base + (size_t)nt * 16 * SEQ + k0;
            vfr[t][nt][0] = *(const bf16x8*)(vr + lg * 8);
            vfr[t][nt][1] = *(const bf16x8*)(vr + 32 + lg * 8);
        }
    }
#pragma unroll
    for (int t = 0; t < 2; ++t)
#pragma unroll
        for (int nt = 0; nt < 4; ++nt) { keep(vfr[t][nt][0]); keep(vfr[t][nt][1]); }

    f32x4 acc_o[4];
#pragma unroll
    for (int nt = 0; nt < 4; ++nt) acc_o[nt] = (f32x4){0.f, 0.f, 0.f, 0.f};
#pragma unroll
    for (int t = 0; t < 2; ++t) {
        bf16x8 pa0 = *(const bf16x8*)&P[w][lr * 136 + t * 64 + lg * 8];
        bf16x8 pa1 = *(const bf16x8*)&P[w][lr * 136 + t * 64 + 32 + lg * 8];
#pragma unroll
        for (int nt = 0; nt < 4; ++nt) {
            acc_o[nt] = __builtin_amdgcn_mfma_f32_16x16x32_bf16(pa0, vfr[t][nt][0], acc_o[nt], 0, 0, 0);
            acc_o[nt] = __builtin_amdgcn_mfma_f32_16x16x32_bf16(pa1, vfr[t][nt][1], acc_o[nt], 0, 0, 0);
        }
    }

    LDS_BARRIER();                                     // sync2: bins done, P dead

    // ---- w2 slice: t-range [w*32, w*32+32) ----
    {
        const uint* sp = &sbin[lr * 132 + w * 32 + lg * 8];
        bf16x8 af = pack8((float)sp[0] * INV_FIX, (float)sp[1] * INV_FIX,
                          (float)sp[2] * INV_FIX, (float)sp[3] * INV_FIX,
                          (float)sp[4] * INV_FIX, (float)sp[5] * INV_FIX,
                          (float)sp[6] * INV_FIX, (float)sp[7] * INV_FIX);
#pragma unroll
        for (int nt = 0; nt < 4; ++nt) {
            bf16x8 bf_ = *(const bf16x8*)(tvT + (size_t)(nt * 16 + lr) * 128 + w * 32 + lg * 8);
            acc_o[nt] = __builtin_amdgcn_mfma_f32_16x16x32_bf16(af, bf_, acc_o[nt], 0, 0, 0);
        }
    }

    // ---- cross-wave O reduction through dead P region ----
    float* obuf = (float*)&P[0][0];
    if (w != 0) {
#pragma unroll
        for (int nt = 0; nt < 4; ++nt)
            *(f32x4*)&obuf[(((w - 1) * 4 + nt) * 64 + l) * 4] = acc_o[nt];
    }
    LDS_BARRIER();                                     // sync3

    if (w == 0) {
#pragma unroll
        for (int j = 0; j < 3; ++j)
#pragma unroll
            for (int nt = 0; nt < 4; ++nt) {
                f32x4 p_ = *(const f32x4*)&obuf[((j * 4 + nt) * 64 + l) * 4];
                acc_o[nt][0] += p_[0]; acc_o[nt][1] += p_[1];
                acc_o[nt][2] += p_[2]; acc_o[nt][3] += p_[3];
            }
        float iv[4], nb[4];
#pragma unroll
        for (int r = 0; r < 4; ++r) {
            const int q = lg * 4 + r;
            iv[r] = 1.f / (rowsumw[0][q] + rowsumw[1][q] + rowsumw[2][q] + rowsumw[3][q]);
            nb[r] = (float)sbin[q * 132 + 128] * INV_FIX;   // t=128 tail bin
        }
        ushort* orow = x + (bSEQ + q0 + lg * 4) * HID + hHD;
#pragma unroll
        for (int nt = 0; nt < 4; ++nt) {
            float tv = table_v[(size_t)128 * HD + nt * 16 + lr];
#pragma unroll
            for (int r = 0; r < 4; ++r) {
                float o = (acc_o[nt][r] + nb[r] * tv) * iv[r];
                orow[(size_t)r * HID + nt * 16 + lr] = f2b(o);
            }
        }
    }
}

// ---------------------------------------------------------------------------
extern "C" void kernel_launch(void* const* d_in, const int* in_sizes, int n_in,
                              void* d_out, int out_size, void* d_ws, size_t ws_size,
                              hipStream_t stream) {
    const float* query = (const float*)d_in[0];
    const float* key   = (const float*)d_in[1];
    const float* value = (const float*)d_in[2];
    const int*   fmat  = (const int*)d_in[3];
    const float* Wq = (const float*)d_in[4];
    const float* bq = (const float*)d_in[5];
    const float* Wk = (const float*)d_in[6];
    const float* bk = (const float*)d_in[7];
    const float* Wv = (const float*)d_in[8];
    const float* bv = (const float*)d_in[9];
    const float* Wo = (const float*)d_in[10];
    const float* bo = (const float*)d_in[11];
    const float* table_k = (const float*)d_in[12];
    const float* table_v = (const float*)d_in[13];

    const size_t nBLD = (size_t)BATCH * SEQ * HID;   // 4,194,304
    const size_t nW   = (size_t)HID * HID;           // 1,048,576
    ushort* us = (ushort*)d_ws;
    ushort* qin16 = us;                 us += nBLD;   // later reused as vT
    ushort* kin16 = us;                 us += nBLD;   // later reused as tvT
    ushort* vin16 = us;                 us += nBLD;
    ushort* wq16  = us;                 us += nW;
    ushort* wk16  = us;                 us += nW;
    ushort* wv16  = us;                 us += nW;
    ushort* wo16  = us;                 us += nW;
    ushort* qb16  = us;                 us += nBLD;
    ushort* kb16  = us;                 us += nBLD;
    ushort* vb16  = us;                 us += nBLD;
    ushort* qt16  = us;                 us += (size_t)BATCH * HEADS * SEQ * QSTR;
    ushort* xb16  = us;                 us += nBLD;
    uchar*  fm8   = (uchar*)us;        // B*L*L bytes = 2,097,152

    ConvArgs ca;
    ca.src[0] = query; ca.src[1] = key; ca.src[2] = value;
    ca.src[3] = Wq; ca.src[4] = Wk; ca.src[5] = Wv; ca.src[6] = Wo;
    ca.dst[0] = qin16; ca.dst[1] = kin16; ca.dst[2] = vin16;
    ca.dst[3] = wq16; ca.dst[4] = wk16; ca.dst[5] = wv16; ca.dst[6] = wo16;
    convert_bf16<<<dim3(8192), 256, 0, stream>>>(ca);

    const int M = BATCH * SEQ;  // 4096

    GemmArgs gq = {};
    gq.A[0] = qin16; gq.A[1] = kin16; gq.A[2] = vin16;
    gq.W[0] = wq16;  gq.W[1] = wk16;  gq.W[2] = wv16;
    gq.bias[0] = bq; gq.bias[1] = bk; gq.bias[2] = bv;
    gq.Cf[0] = nullptr; gq.Cf[1] = nullptr; gq.Cf[2] = nullptr;
    gq.Cb[0] = qb16; gq.Cb[1] = kb16; gq.Cb[2] = vb16;
    gemm_bf16<<<dim3(HID / 128, M / 128, 3), 256, 0, stream>>>(gq, M, HID, HID);

    // qin16/kin16 are dead after the QKV GEMM: reuse as vT / tvT
    ushort* vTbuf  = qin16;   // [B,H,64,512] bf16
    ushort* tvTbuf = kin16;   // [64,128] bf16

    // fused: qtab + V transpose + tvT + fm->u8  (769 + 1024 blocks)
    prep_kernel<<<dim3(1793), 256, 0, stream>>>(qb16, table_k, vb16, table_v,
                                                fmat, qt16, vTbuf, tvTbuf, fm8);

    attn_mfma<<<dim3(BATCH * HEADS * (SEQ/16)), 256, 0, stream>>>(
        qb16, kb16, vTbuf, qt16, fm8, table_v, tvTbuf, xb16);

    gemm_wo<<<dim3(HID / 64, M / 128), 256, 0, stream>>>(xb16, wo16, bo, (float*)d_out);
}

// Round 13
// 188.710 us; speedup vs baseline: 1.0527x; 1.0527x over previous
//
#include <hip/hip_runtime.h>

#define HID 1024
#define HEADS 16
#define HD 64
#define TAB 129
#define QSTR 136
#define BATCH 8
#define SEQ 512

typedef unsigned int uint;
typedef unsigned short ushort;
typedef unsigned char uchar;
typedef __attribute__((ext_vector_type(4))) float f32x4;
typedef __attribute__((ext_vector_type(8))) __bf16 bf16x8;

__device__ __forceinline__ ushort f2b(float x) {
    uint b = __float_as_uint(x);
    uint r = (b + 0x7fffu + ((b >> 16) & 1u)) >> 16;
    return (ushort)r;
}
__device__ __forceinline__ uint pk(float lo, float hi) {
    return (uint)f2b(lo) | ((uint)f2b(hi) << 16);
}
__device__ __forceinline__ float b2f(ushort u) {
    return __uint_as_float(((uint)u) << 16);
}
union U16x8 { uint u[4]; bf16x8 v; ushort s[8]; uint4 q; };

#define GL16(gp, lp) __builtin_amdgcn_global_load_lds( \
    (const __attribute__((address_space(1))) void*)(gp), \
    (__attribute__((address_space(3))) void*)(lp), 16, 0, 0)

// ---------------------------------------------------------------------------
// convert fp32 -> bf16 (unchanged)
// ---------------------------------------------------------------------------
struct ConvArgs { const float* src[7]; ushort* dst[7]; };

__global__ __launch_bounds__(256) void convert_bf16(ConvArgs ca) {
    int bid = blockIdx.x;
    int ti, lb;
    if (bid < 6144) { ti = bid >> 11; lb = bid & 2047; }
    else { int r = bid - 6144; ti = 3 + (r >> 9); lb = r & 511; }
    const float* s = ca.src[ti] + (size_t)lb * 2048 + (threadIdx.x << 3);
    ushort*      d = ca.dst[ti] + (size_t)lb * 2048 + (threadIdx.x << 3);
    float4 a = *(const float4*)s;
    float4 c = *(const float4*)(s + 4);
    uint4 u;
    u.x = pk(a.x, a.y); u.y = pk(a.z, a.w);
    u.z = pk(c.x, c.y); u.w = pk(c.z, c.w);
    *(uint4*)d = u;
}

// ---------------------------------------------------------------------------
// bf16 MFMA GEMM (QKV, unchanged)
// ---------------------------------------------------------------------------
struct GemmArgs {
    const ushort* A[3];
    const ushort* W[3];
    const float*  bias[3];
    float*        Cf[3];
    ushort*       Cb[3];
};

__global__ __launch_bounds__(256) void gemm_bf16(GemmArgs ga, int M, int N, int K) {
    __shared__ ushort As[2][128 * 32];
    __shared__ ushort Bs[2][128 * 32];
    const int z = blockIdx.z;
    const ushort* A = ga.A[z];
    const ushort* W = ga.W[z];
    const int tid = threadIdx.x;
    const int m0 = blockIdx.y * 128;
    const int n0 = blockIdx.x * 128;

    const int w  = tid >> 6;
    const int l  = tid & 63;
    const int lr = l & 15;
    const int lg = l >> 4;
    const int wm = w >> 1;
    const int wn = w & 1;

    const int sr = tid >> 2;
    const int sc = tid & 3;
    const int g  = sc ^ ((sr >> 1) & 3);
    const ushort* Ag0 = A + (size_t)(m0 + sr)      * K + g * 8;
    const ushort* Ag1 = A + (size_t)(m0 + sr + 64) * K + g * 8;
    const ushort* Wg0 = W + (size_t)(n0 + sr)      * K + g * 8;
    const ushort* Wg1 = W + (size_t)(n0 + sr + 64) * K + g * 8;

    f32x4 acc[4][4];
#pragma unroll
    for (int mt = 0; mt < 4; ++mt)
#pragma unroll
        for (int nt = 0; nt < 4; ++nt) acc[mt][nt] = (f32x4){0.f, 0.f, 0.f, 0.f};

#define STAGE(buf, k0) do { \
        GL16(Ag0 + (k0), &As[buf][w * 512]); \
        GL16(Ag1 + (k0), &As[buf][2048 + w * 512]); \
        GL16(Wg0 + (k0), &Bs[buf][w * 512]); \
        GL16(Wg1 + (k0), &Bs[buf][2048 + w * 512]); \
    } while (0)

    const int swz = (lr >> 1) & 3;
#define COMPUTE(buf) do { \
        bf16x8 af[4], bf[4]; \
        _Pragma("unroll") \
        for (int mt = 0; mt < 4; ++mt) \
            af[mt] = *(const bf16x8*)&As[buf][(wm * 64 + mt * 16 + lr) * 32 + (lg ^ swz) * 8]; \
        _Pragma("unroll") \
        for (int nt = 0; nt < 4; ++nt) \
            bf[nt] = *(const bf16x8*)&Bs[buf][(wn * 64 + nt * 16 + lr) * 32 + (lg ^ swz) * 8]; \
        _Pragma("unroll") \
        for (int mt = 0; mt < 4; ++mt) \
            _Pragma("unroll") \
            for (int nt = 0; nt < 4; ++nt) \
                acc[mt][nt] = __builtin_amdgcn_mfma_f32_16x16x32_bf16(af[mt], bf[nt], acc[mt][nt], 0, 0, 0); \
    } while (0)

    STAGE(0, 0);
    __syncthreads();
    const int nk = K / 32;
    for (int t = 0; t < nk - 1; ++t) {
        STAGE((t + 1) & 1, (size_t)(t + 1) * 32);
        COMPUTE(t & 1);
        __syncthreads();
    }
    COMPUTE((nk - 1) & 1);

    const float* bias = ga.bias[z];
    float bv[4];
#pragma unroll
    for (int nt = 0; nt < 4; ++nt) bv[nt] = bias[n0 + wn * 64 + nt * 16 + lr];
    float*  Cf = ga.Cf[z];
    ushort* Cb = ga.Cb[z];
    if (Cf) {
#pragma unroll
        for (int mt = 0; mt < 4; ++mt)
#pragma unroll
            for (int r4 = 0; r4 < 4; ++r4) {
                size_t m = m0 + wm * 64 + mt * 16 + lg * 4 + r4;
                float* crow = Cf + m * N + n0 + wn * 64 + lr;
#pragma unroll
                for (int nt = 0; nt < 4; ++nt)
                    crow[nt * 16] = acc[mt][nt][r4] + bv[nt];
            }
    } else {
#pragma unroll
        for (int mt = 0; mt < 4; ++mt)
#pragma unroll
            for (int r4 = 0; r4 < 4; ++r4) {
                size_t m = m0 + wm * 64 + mt * 16 + lg * 4 + r4;
                ushort* crow = Cb + m * N + n0 + wn * 64 + lr;
#pragma unroll
                for (int nt = 0; nt < 4; ++nt)
                    crow[nt * 16] = f2b(acc[mt][nt][r4] + bv[nt]);
            }
    }
#undef STAGE
#undef COMPUTE
}

// ---------------------------------------------------------------------------
// Wo GEMM, BN=64 tile (unchanged R11)
// ---------------------------------------------------------------------------
__global__ __launch_bounds__(256) void gemm_wo(const ushort* __restrict__ A,
                                               const ushort* __restrict__ W,
                                               const float* __restrict__ bias,
                                               float* __restrict__ Cf) {
    const int M = BATCH * SEQ, N = HID, K = HID;
    __shared__ ushort As[2][128 * 32];
    __shared__ ushort Bs[2][64 * 32];
    const int tid = threadIdx.x;
    const int m0 = blockIdx.y * 128;
    const int n0 = blockIdx.x * 64;

    const int w  = tid >> 6;
    const int l  = tid & 63;
    const int lr = l & 15;
    const int lg = l >> 4;
    const int wm = w >> 1;
    const int wn = w & 1;

    const int sr = tid >> 2;
    const int sc = tid & 3;
    const int g  = sc ^ ((sr >> 1) & 3);
    const ushort* Ag0 = A + (size_t)(m0 + sr)      * K + g * 8;
    const ushort* Ag1 = A + (size_t)(m0 + sr + 64) * K + g * 8;
    const ushort* Wg0 = W + (size_t)(n0 + sr)      * K + g * 8;

    f32x4 acc[4][2];
#pragma unroll
    for (int mt = 0; mt < 4; ++mt)
#pragma unroll
        for (int nt = 0; nt < 2; ++nt) acc[mt][nt] = (f32x4){0.f, 0.f, 0.f, 0.f};

#define STAGE(buf, k0) do { \
        GL16(Ag0 + (k0), &As[buf][w * 512]); \
        GL16(Ag1 + (k0), &As[buf][2048 + w * 512]); \
        GL16(Wg0 + (k0), &Bs[buf][w * 512]); \
    } while (0)

    const int swz = (lr >> 1) & 3;
#define COMPUTE(buf) do { \
        bf16x8 af[4], bf[2]; \
        _Pragma("unroll") \
        for (int mt = 0; mt < 4; ++mt) \
            af[mt] = *(const bf16x8*)&As[buf][(wm * 64 + mt * 16 + lr) * 32 + (lg ^ swz) * 8]; \
        _Pragma("unroll") \
        for (int nt = 0; nt < 2; ++nt) \
            bf[nt] = *(const bf16x8*)&Bs[buf][(wn * 32 + nt * 16 + lr) * 32 + (lg ^ swz) * 8]; \
        _Pragma("unroll") \
        for (int mt = 0; mt < 4; ++mt) \
            _Pragma("unroll") \
            for (int nt = 0; nt < 2; ++nt) \
                acc[mt][nt] = __builtin_amdgcn_mfma_f32_16x16x32_bf16(af[mt], bf[nt], acc[mt][nt], 0, 0, 0); \
    } while (0)

    STAGE(0, 0);
    __syncthreads();
    const int nk = K / 32;
    for (int t = 0; t < nk - 1; ++t) {
        STAGE((t + 1) & 1, (size_t)(t + 1) * 32);
        COMPUTE(t & 1);
        __syncthreads();
    }
    COMPUTE((nk - 1) & 1);

    float bv[2];
#pragma unroll
    for (int nt = 0; nt < 2; ++nt) bv[nt] = bias[n0 + wn * 32 + nt * 16 + lr];
#pragma unroll
    for (int mt = 0; mt < 4; ++mt)
#pragma unroll
        for (int r4 = 0; r4 < 4; ++r4) {
            size_t m = m0 + wm * 64 + mt * 16 + lg * 4 + r4;
            float* crow = Cf + m * N + n0 + wn * 32 + lr;
#pragma unroll
            for (int nt = 0; nt < 2; ++nt)
                crow[nt * 16] = acc[mt][nt][r4] + bv[nt];
        }
#undef STAGE
#undef COMPUTE
}

// ---------------------------------------------------------------------------
// prep_kernel: qtab (MFMA) + V-transpose + tvT2 (padded [64][160]) + fm->u8
// ---------------------------------------------------------------------------
__global__ __launch_bounds__(256) void prep_kernel(const ushort* __restrict__ qb,
                                                   const float* __restrict__ table_k,
                                                   const ushort* __restrict__ vb,
                                                   const float* __restrict__ table_v,
                                                   const int* __restrict__ fmat,
                                                   ushort* __restrict__ qtab,
                                                   ushort* __restrict__ vT,
                                                   ushort* __restrict__ tvT2,
                                                   uchar* __restrict__ fm8) {
    __shared__ __align__(16) ushort shmem[144 * 72];
    const int wg  = blockIdx.x;
    const int tid = threadIdx.x;

    if (wg < 256) {
        const int h    = wg & 15;
        const int half = (wg >> 4) & 1;
        const int b    = wg >> 5;
        const int q0   = half * 256;
        ushort* tk = shmem;
        for (int i = tid; i < TAB * 8; i += 256) {
            int row = i >> 3, gr = i & 7;
            const float* src = table_k + row * HD + gr * 8;
            float4 a = *(const float4*)src;
            float4 c = *(const float4*)(src + 4);
            uint4 u;
            u.x = pk(a.x, a.y); u.y = pk(a.z, a.w);
            u.z = pk(c.x, c.y); u.w = pk(c.z, c.w);
            *(uint4*)&tk[row * 72 + gr * 8] = u;
        }
        __syncthreads();

        const int w  = tid >> 6;
        const int l  = tid & 63;
        const int lr = l & 15;
        const int lg = l >> 4;
        bf16x8 qf[4][2];
#pragma unroll
        for (int qt = 0; qt < 4; ++qt) {
            const ushort* qrow = qb + ((size_t)(b * SEQ) + q0 + w * 64 + qt * 16 + lr) * HID + h * HD;
            qf[qt][0] = *(const bf16x8*)(qrow + lg * 8);
            qf[qt][1] = *(const bf16x8*)(qrow + 32 + lg * 8);
        }
        ushort* outbase = qtab + ((size_t)(b * HEADS + h) * SEQ + q0 + w * 64) * QSTR;
#pragma unroll
        for (int mt = 0; mt < 9; ++mt) {
            bf16x8 tf0 = *(const bf16x8*)&tk[(mt * 16 + lr) * 72 + lg * 8];
            bf16x8 tf1 = *(const bf16x8*)&tk[(mt * 16 + lr) * 72 + 32 + lg * 8];
#pragma unroll
            for (int qt = 0; qt < 4; ++qt) {
                f32x4 acc = (f32x4){0.f, 0.f, 0.f, 0.f};
                acc = __builtin_amdgcn_mfma_f32_16x16x32_bf16(tf0, qf[qt][0], acc, 0, 0, 0);
                acc = __builtin_amdgcn_mfma_f32_16x16x32_bf16(tf1, qf[qt][1], acc, 0, 0, 0);
                ushort* orow = outbase + (size_t)(qt * 16 + lr) * QSTR;
                if (mt < 8) {
                    uint2 pu;
                    pu.x = pk(acc[0], acc[1]); pu.y = pk(acc[2], acc[3]);
                    *(uint2*)&orow[mt * 16 + lg * 4] = pu;
                } else if (lg == 0) {
                    orow[128] = f2b(acc[0]);
                }
            }
        }
    } else if (wg < 768) {
        const int vw = wg - 256;
        ushort* tile = shmem;
        const int b = vw >> 6, h = (vw >> 2) & 15, kc = vw & 3;
        const int k0 = kc * 128;
        {
            const int kr = tid >> 1, dc = (tid & 1) * 32;
            const ushort* src = vb + ((size_t)(b * SEQ) + k0 + kr) * HID + h * 64 + dc;
#pragma unroll
            for (int j = 0; j < 4; ++j) {
                uint4 u = *(const uint4*)(src + j * 8);
                *(uint4*)&tile[kr * 72 + dc + j * 8] = u;
            }
        }
        __syncthreads();
        {
            const int dr = tid >> 2, kc2 = (tid & 3) * 32;
            ushort* dst = vT + ((size_t)(b * 16 + h) * 64 + dr) * 512 + k0 + kc2;
#pragma unroll
            for (int j = 0; j < 4; ++j) {
                U16x8 o;
#pragma unroll
                for (int i = 0; i < 8; ++i)
                    o.s[i] = tile[(kc2 + j * 8 + i) * 72 + dr];
                *(uint4*)(dst + j * 8) = o.q;
            }
        }
    } else if (wg == 768) {
        // tvT2[d][c]: c<129 -> table_v[c][d], else 0  (stride 160)
        for (int i = tid; i < 64 * 160; i += 256) {
            int d = i / 160;
            int c = i - d * 160;
            tvT2[i] = (c < TAB) ? f2b(table_v[(size_t)c * HD + d]) : (ushort)0;
        }
    } else {
        const size_t base = (size_t)(wg - 769) * 2048 + (size_t)tid * 8;
        int4 a = *(const int4*)(fmat + base);
        int4 c = *(const int4*)(fmat + base + 4);
        uint lo = (uint)a.x | ((uint)a.y << 8) | ((uint)a.z << 16) | ((uint)a.w << 24);
        uint hi = (uint)c.x | ((uint)c.y << 8) | ((uint)c.z << 16) | ((uint)c.w << 24);
        uint2 o; o.x = lo; o.y = hi;
        *(uint2*)(fm8 + base) = o;
    }
}

// ---------------------------------------------------------------------------
// qk_gemm: S[bh, q, k] = Q . K^T  (bf16 out). M=N=512, K=64 per bh.
// grid (4, 4, 128); gemm_bf16 frag structure; both k-halves staged upfront.
// ---------------------------------------------------------------------------
__global__ __launch_bounds__(256) void qk_gemm(const ushort* __restrict__ qb,
                                               const ushort* __restrict__ kb,
                                               ushort* __restrict__ S) {
    __shared__ ushort As[2][128 * 32];
    __shared__ ushort Bs[2][128 * 32];
    const int tid = threadIdx.x;
    const int m0 = blockIdx.x * 128;
    const int n0 = blockIdx.y * 128;
    const int bh = blockIdx.z;
    const int b = bh >> 4, h = bh & 15;
    const size_t rowQ = (size_t)b * SEQ;

    const int w  = tid >> 6;
    const int l  = tid & 63;
    const int lr = l & 15;
    const int lg = l >> 4;
    const int wm = w >> 1;
    const int wn = w & 1;

    const int sr = tid >> 2;
    const int sc = tid & 3;
    const int g  = sc ^ ((sr >> 1) & 3);
    const ushort* Ag0 = qb + (rowQ + m0 + sr)      * HID + h * HD + g * 8;
    const ushort* Ag1 = qb + (rowQ + m0 + sr + 64) * HID + h * HD + g * 8;
    const ushort* Wg0 = kb + (rowQ + n0 + sr)      * HID + h * HD + g * 8;
    const ushort* Wg1 = kb + (rowQ + n0 + sr + 64) * HID + h * HD + g * 8;

    GL16(Ag0,      &As[0][w * 512]); GL16(Ag1,      &As[0][2048 + w * 512]);
    GL16(Wg0,      &Bs[0][w * 512]); GL16(Wg1,      &Bs[0][2048 + w * 512]);
    GL16(Ag0 + 32, &As[1][w * 512]); GL16(Ag1 + 32, &As[1][2048 + w * 512]);
    GL16(Wg0 + 32, &Bs[1][w * 512]); GL16(Wg1 + 32, &Bs[1][2048 + w * 512]);

    f32x4 acc[4][4];
#pragma unroll
    for (int mt = 0; mt < 4; ++mt)
#pragma unroll
        for (int nt = 0; nt < 4; ++nt) acc[mt][nt] = (f32x4){0.f, 0.f, 0.f, 0.f};

    const int swz = (lr >> 1) & 3;
    __syncthreads();
#pragma unroll
    for (int buf = 0; buf < 2; ++buf) {
        bf16x8 af[4], bf[4];
#pragma unroll
        for (int mt = 0; mt < 4; ++mt)
            af[mt] = *(const bf16x8*)&As[buf][(wm * 64 + mt * 16 + lr) * 32 + (lg ^ swz) * 8];
#pragma unroll
        for (int nt = 0; nt < 4; ++nt)
            bf[nt] = *(const bf16x8*)&Bs[buf][(wn * 64 + nt * 16 + lr) * 32 + (lg ^ swz) * 8];
#pragma unroll
        for (int mt = 0; mt < 4; ++mt)
#pragma unroll
            for (int nt = 0; nt < 4; ++nt)
                acc[mt][nt] = __builtin_amdgcn_mfma_f32_16x16x32_bf16(af[mt], bf[nt], acc[mt][nt], 0, 0, 0);
    }

    // write S bf16 (scalar 2B stores, 16 lanes contiguous per instr)
    ushort* Sb = S + (size_t)bh * SEQ * SEQ;
#pragma unroll
    for (int mt = 0; mt < 4; ++mt)
#pragma unroll
        for (int r4 = 0; r4 < 4; ++r4) {
            int m = m0 + wm * 64 + mt * 16 + lg * 4 + r4;
            ushort* srow = Sb + (size_t)m * SEQ + n0 + wn * 64 + lr;
#pragma unroll
            for (int nt = 0; nt < 4; ++nt)
                srow[nt * 16] = f2b(acc[mt][nt][r4]);
        }
}

// ---------------------------------------------------------------------------
// sm_kernel: per q-row softmax + relative-position gather + bin histogram.
// One wave per row; 8 rows/wave; zero barriers. P overwrites S in place.
// ---------------------------------------------------------------------------
__global__ __launch_bounds__(256) void sm_kernel(ushort* __restrict__ S,
                                                 const ushort* __restrict__ qt,
                                                 const uchar* __restrict__ fm8,
                                                 ushort* __restrict__ binbuf) {
    constexpr float FIX = 65536.0f;
    constexpr float INV_FIX = 1.0f / 65536.0f;
    __shared__ uint binsL[4][160];
    const int tid = threadIdx.x;
    const int wv  = tid >> 6;
    const int l   = tid & 63;
    const int gr0 = blockIdx.x * 32 + wv * 8;

    for (int ri = 0; ri < 8; ++ri) {
        const int gr = gr0 + ri;                 // global row: bh*512 + q
        const int q  = gr & 511;
        const int b  = gr >> 13;
        // zero bins (own wave only)
        binsL[wv][l] = 0u;
        binsL[wv][l + 64] = 0u;
        if (l < 32) binsL[wv][l + 128] = 0u;

        U16x8 sv;
        sv.q = *(const uint4*)&S[((size_t)gr << 9) + l * 8];
        const uchar* fr = fm8 + ((((size_t)b << 9) + q) << 9) + l * 8;
        uint f0 = *(const uint*)fr;
        uint f1 = *(const uint*)(fr + 4);
        const ushort* qrow = qt + (size_t)gr * QSTR;

        int ts[8];
        ts[0] = f0 & 255; ts[1] = (f0 >> 8) & 255; ts[2] = (f0 >> 16) & 255; ts[3] = f0 >> 24;
        ts[4] = f1 & 255; ts[5] = (f1 >> 8) & 255; ts[6] = (f1 >> 16) & 255; ts[7] = f1 >> 24;

        float pr[8];
        float lsum = 0.f;
#pragma unroll
        for (int j = 0; j < 8; ++j) {
            float s = b2f(sv.s[j]);
            float gv = b2f(qrow[ts[j]]);
            pr[j] = __expf((s + gv) * 0.125f);
            lsum += pr[j];
        }
#pragma unroll
        for (int j = 0; j < 8; ++j)
            __hip_atomic_fetch_add(&binsL[wv][ts[j]], (uint)(pr[j] * FIX),
                                   __ATOMIC_RELAXED, __HIP_MEMORY_SCOPE_WORKGROUP);
#pragma unroll
        for (int off = 32; off >= 1; off >>= 1)
            lsum += __shfl_xor(lsum, off);
        const float invl = 1.f / lsum;

        // P = p/l in place over S
        U16x8 pv;
#pragma unroll
        for (int j = 0; j < 4; ++j)
            pv.u[j] = pk(pr[2 * j] * invl, pr[2 * j + 1] * invl);
        *(uint4*)&S[((size_t)gr << 9) + l * 8] = pv.q;

        // bins -> binbuf (normalized, bf16, stride 160 incl. zero pad)
        asm volatile("s_waitcnt lgkmcnt(0)" ::: "memory");
        ushort* bb = binbuf + (size_t)gr * 160;
        const float sc = INV_FIX * invl;
        {
            int c = 2 * l;
            *(uint*)&bb[c] = pk((float)binsL[wv][c] * sc, (float)binsL[wv][c + 1] * sc);
        }
        if (l < 16) {
            int c = 128 + 2 * l;
            *(uint*)&bb[c] = pk((float)binsL[wv][c] * sc, (float)binsL[wv][c + 1] * sc);
        }
    }
}

// ---------------------------------------------------------------------------
// pv_gemm: O[bh, q, d] = P . V^T  +  bins . tvT2   (K = 512 + 160)
// grid (4, 128). M-tile 128, N = 64 (4 waves 2x2), double-buffered.
// ---------------------------------------------------------------------------
__global__ __launch_bounds__(256) void pv_gemm(const ushort* __restrict__ P,
                                               const ushort* __restrict__ binbuf,
                                               const ushort* __restrict__ vT,
                                               const ushort* __restrict__ tvT2,
                                               ushort* __restrict__ x) {
    __shared__ ushort As[2][128 * 32];
    __shared__ ushort Bs[2][64 * 32];
    const int tid = threadIdx.x;
    const int m0 = blockIdx.x * 128;
    const int bh = blockIdx.y;
    const int b = bh >> 4, h = bh & 15;

    const int w  = tid >> 6;
    const int l  = tid & 63;
    const int lr = l & 15;
    const int lg = l >> 4;
    const int wm = w >> 1;
    const int wn = w & 1;

    const int sr = tid >> 2;
    const int sc = tid & 3;
    const int g  = sc ^ ((sr >> 1) & 3);
    const ushort* AgS0 = P + ((size_t)bh * SEQ + m0 + sr)      * 512 + g * 8;
    const ushort* AgS1 = P + ((size_t)bh * SEQ + m0 + sr + 64) * 512 + g * 8;
    const ushort* AgB0 = binbuf + ((size_t)bh * SEQ + m0 + sr)      * 160 + g * 8;
    const ushort* AgB1 = binbuf + ((size_t)bh * SEQ + m0 + sr + 64) * 160 + g * 8;
    const ushort* WgV  = vT + ((size_t)bh * 64 + sr) * 512 + g * 8;
    const ushort* WgT  = tvT2 + (size_t)sr * 160 + g * 8;

#define STAGE_C(buf, st) do { \
        const ushort* a0_ = (st) < 16 ? AgS0 + (st) * 32 : AgB0 + ((st) - 16) * 32; \
        const ushort* a1_ = (st) < 16 ? AgS1 + (st) * 32 : AgB1 + ((st) - 16) * 32; \
        const ushort* b0_ = (st) < 16 ? WgV  + (st) * 32 : WgT  + ((st) - 16) * 32; \
        GL16(a0_, &As[buf][w * 512]); \
        GL16(a1_, &As[buf][2048 + w * 512]); \
        GL16(b0_, &Bs[buf][w * 512]); \
    } while (0)

    f32x4 acc[4][2];
#pragma unroll
    for (int mt = 0; mt < 4; ++mt)
#pragma unroll
        for (int nt = 0; nt < 2; ++nt) acc[mt][nt] = (f32x4){0.f, 0.f, 0.f, 0.f};

    const int swz = (lr >> 1) & 3;
#define COMPUTE_C(buf) do { \
        bf16x8 af[4], bf[2]; \
        _Pragma("unroll") \
        for (int mt = 0; mt < 4; ++mt) \
            af[mt] = *(const bf16x8*)&As[buf][(wm * 64 + mt * 16 + lr) * 32 + (lg ^ swz) * 8]; \
        _Pragma("unroll") \
        for (int nt = 0; nt < 2; ++nt) \
            bf[nt] = *(const bf16x8*)&Bs[buf][(wn * 32 + nt * 16 + lr) * 32 + (lg ^ swz) * 8]; \
        _Pragma("unroll") \
        for (int mt = 0; mt < 4; ++mt) \
            _Pragma("unroll") \
            for (int nt = 0; nt < 2; ++nt) \
                acc[mt][nt] = __builtin_amdgcn_mfma_f32_16x16x32_bf16(af[mt], bf[nt], acc[mt][nt], 0, 0, 0); \
    } while (0)

    STAGE_C(0, 0);
    __syncthreads();
    const int nk = 21;                 // 16 (P) + 5 (bins)
    for (int t = 0; t < nk - 1; ++t) {
        STAGE_C((t + 1) & 1, t + 1);
        COMPUTE_C(t & 1);
        __syncthreads();
    }
    COMPUTE_C((nk - 1) & 1);

    // write x (bf16)
#pragma unroll
    for (int mt = 0; mt < 4; ++mt)
#pragma unroll
        for (int r4 = 0; r4 < 4; ++r4) {
            int m = m0 + wm * 64 + mt * 16 + lg * 4 + r4;
            ushort* orow = x + ((size_t)(b * SEQ) + m) * HID + h * HD + wn * 32 + lr;
#pragma unroll
            for (int nt = 0; nt < 2; ++nt)
                orow[nt * 16] = f2b(acc[mt][nt][r4]);
        }
#undef STAGE_C
#undef COMPUTE_C
}

// ---------------------------------------------------------------------------
extern "C" void kernel_launch(void* const* d_in, const int* in_sizes, int n_in,
                              void* d_out, int out_size, void* d_ws, size_t ws_size,
                              hipStream_t stream) {
    const float* query = (const float*)d_in[0];
    const float* key   = (const float*)d_in[1];
    const float* value = (const float*)d_in[2];
    const int*   fmat  = (const int*)d_in[3];
    const float* Wq = (const float*)d_in[4];
    const float* bq = (const float*)d_in[5];
    const float* Wk = (const float*)d_in[6];
    const float* bk = (const float*)d_in[7];
    const float* Wv = (const float*)d_in[8];
    const float* bv = (const float*)d_in[9];
    const float* Wo = (const float*)d_in[10];
    const float* bo = (const float*)d_in[11];
    const float* table_k = (const float*)d_in[12];
    const float* table_v = (const float*)d_in[13];

    const size_t nBLD = (size_t)BATCH * SEQ * HID;   // 4,194,304
    const size_t nW   = (size_t)HID * HID;           // 1,048,576
    ushort* us = (ushort*)d_ws;
    ushort* qin16 = us;                 us += nBLD;   // reused as vT
    ushort* kin16 = us;                 us += nBLD;   // reused as tvT2
    ushort* vin16 = us;                 us += nBLD;
    ushort* wq16  = us;                 us += nW;
    ushort* wk16  = us;                 us += nW;
    ushort* wv16  = us;                 us += nW;
    ushort* wo16  = us;                 us += nW;
    ushort* qb16  = us;                 us += nBLD;
    ushort* kb16  = us;                 us += nBLD;
    ushort* vb16  = us;                 us += nBLD;
    ushort* qt16  = us;                 us += (size_t)BATCH * HEADS * SEQ * QSTR;
    ushort* xb16  = us;                 us += nBLD;
    uchar*  fm8   = (uchar*)us;         us += (size_t)BATCH * SEQ * SEQ / 2;  // 2MB
    ushort* Sbuf  = us;                 us += (size_t)BATCH * HEADS * SEQ * SEQ;  // 67MB
    ushort* binbf = us;                 us += (size_t)BATCH * HEADS * SEQ * 160;  // 21MB

    ConvArgs ca;
    ca.src[0] = query; ca.src[1] = key; ca.src[2] = value;
    ca.src[3] = Wq; ca.src[4] = Wk; ca.src[5] = Wv; ca.src[6] = Wo;
    ca.dst[0] = qin16; ca.dst[1] = kin16; ca.dst[2] = vin16;
    ca.dst[3] = wq16; ca.dst[4] = wk16; ca.dst[5] = wv16; ca.dst[6] = wo16;
    convert_bf16<<<dim3(8192), 256, 0, stream>>>(ca);

    const int M = BATCH * SEQ;  // 4096

    GemmArgs gq = {};
    gq.A[0] = qin16; gq.A[1] = kin16; gq.A[2] = vin16;
    gq.W[0] = wq16;  gq.W[1] = wk16;  gq.W[2] = wv16;
    gq.bias[0] = bq; gq.bias[1] = bk; gq.bias[2] = bv;
    gq.Cf[0] = nullptr; gq.Cf[1] = nullptr; gq.Cf[2] = nullptr;
    gq.Cb[0] = qb16; gq.Cb[1] = kb16; gq.Cb[2] = vb16;
    gemm_bf16<<<dim3(HID / 128, M / 128, 3), 256, 0, stream>>>(gq, M, HID, HID);

    ushort* vTbuf  = qin16;   // [B,H,64,512] bf16 (dead input buffer)
    ushort* tvTbuf = kin16;   // [64,160] bf16

    prep_kernel<<<dim3(1793), 256, 0, stream>>>(qb16, table_k, vb16, table_v,
                                                fmat, qt16, vTbuf, tvTbuf, fm8);

    // attention as three regular kernels
    qk_gemm<<<dim3(4, 4, 128), 256, 0, stream>>>(qb16, kb16, Sbuf);
    sm_kernel<<<dim3(BATCH * HEADS * SEQ / 32), 256, 0, stream>>>(Sbuf, qt16, fm8, binbf);
    pv_gemm<<<dim3(4, 128), 256, 0, stream>>>(Sbuf, binbf, vTbuf, tvTbuf, xb16);

    gemm_wo<<<dim3(HID / 64, M / 128), 256, 0, stream>>>(xb16, wo16, bo, (float*)d_out);
}

// Round 14
// 178.796 us; speedup vs baseline: 1.1110x; 1.0554x over previous
//
#include <hip/hip_runtime.h>

#define HID 1024
#define HEADS 16
#define HD 64
#define TAB 129
#define QSTR 136
#define BATCH 8
#define SEQ 512

typedef unsigned int uint;
typedef unsigned short ushort;
typedef unsigned char uchar;
typedef __attribute__((ext_vector_type(4))) float f32x4;
typedef __attribute__((ext_vector_type(8))) __bf16 bf16x8;

__device__ __forceinline__ ushort f2b(float x) {
    uint b = __float_as_uint(x);
    uint r = (b + 0x7fffu + ((b >> 16) & 1u)) >> 16;
    return (ushort)r;
}
__device__ __forceinline__ uint pk(float lo, float hi) {
    return (uint)f2b(lo) | ((uint)f2b(hi) << 16);
}
__device__ __forceinline__ float b2f(ushort u) {
    return __uint_as_float(((uint)u) << 16);
}
union U16x8 { uint u[4]; bf16x8 v; ushort s[8]; uint4 q; };

#define GL16(gp, lp) __builtin_amdgcn_global_load_lds( \
    (const __attribute__((address_space(1))) void*)(gp), \
    (__attribute__((address_space(3))) void*)(lp), 16, 0, 0)

// ---------------------------------------------------------------------------
// convert fp32 -> bf16 (unchanged)
// ---------------------------------------------------------------------------
struct ConvArgs { const float* src[7]; ushort* dst[7]; };

__global__ __launch_bounds__(256) void convert_bf16(ConvArgs ca) {
    int bid = blockIdx.x;
    int ti, lb;
    if (bid < 6144) { ti = bid >> 11; lb = bid & 2047; }
    else { int r = bid - 6144; ti = 3 + (r >> 9); lb = r & 511; }
    const float* s = ca.src[ti] + (size_t)lb * 2048 + (threadIdx.x << 3);
    ushort*      d = ca.dst[ti] + (size_t)lb * 2048 + (threadIdx.x << 3);
    float4 a = *(const float4*)s;
    float4 c = *(const float4*)(s + 4);
    uint4 u;
    u.x = pk(a.x, a.y); u.y = pk(a.z, a.w);
    u.z = pk(c.x, c.y); u.w = pk(c.z, c.w);
    *(uint4*)d = u;
}

// ---------------------------------------------------------------------------
// QKV GEMM: BN=64 tiles, z-batched, XCD-bijective swizzled 1D grid (1536 blk).
// C_z = A_z @ W_z^T + bias_z, bf16 out.  6 blocks/CU, 24KB LDS.
// ---------------------------------------------------------------------------
struct GemmArgs {
    const ushort* A[3];
    const ushort* W[3];
    const float*  bias[3];
    ushort*       Cb[3];
};

__global__ __launch_bounds__(256) void gemm_qkv(GemmArgs ga) {
    const int N = HID, K = HID;
    __shared__ ushort As[2][128 * 32];
    __shared__ ushort Bs[2][64 * 32];
    const int tid = threadIdx.x;
    // bijective XCD swizzle: 1536 blocks, 192/XCD chunk
    const int bid = blockIdx.x;
    const int swz = (bid & 7) * 192 + (bid >> 3);
    const int z   = swz >> 9;            // 0..2
    const int rem = swz & 511;           // 32 m-tiles x 16 n-tiles
    const int m0  = (rem >> 4) * 128;
    const int n0  = (rem & 15) * 64;
    const ushort* A = ga.A[z];
    const ushort* W = ga.W[z];

    const int w  = tid >> 6;
    const int l  = tid & 63;
    const int lr = l & 15;
    const int lg = l >> 4;
    const int wm = w >> 1;
    const int wn = w & 1;

    const int sr = tid >> 2;
    const int sc = tid & 3;
    const int g  = sc ^ ((sr >> 1) & 3);
    const ushort* Ag0 = A + (size_t)(m0 + sr)      * K + g * 8;
    const ushort* Ag1 = A + (size_t)(m0 + sr + 64) * K + g * 8;
    const ushort* Wg0 = W + (size_t)(n0 + sr)      * K + g * 8;

    f32x4 acc[4][2];
#pragma unroll
    for (int mt = 0; mt < 4; ++mt)
#pragma unroll
        for (int nt = 0; nt < 2; ++nt) acc[mt][nt] = (f32x4){0.f, 0.f, 0.f, 0.f};

#define STAGE(buf, k0) do { \
        GL16(Ag0 + (k0), &As[buf][w * 512]); \
        GL16(Ag1 + (k0), &As[buf][2048 + w * 512]); \
        GL16(Wg0 + (k0), &Bs[buf][w * 512]); \
    } while (0)

    const int swl = (lr >> 1) & 3;
#define COMPUTE(buf) do { \
        bf16x8 af[4], bf[2]; \
        _Pragma("unroll") \
        for (int mt = 0; mt < 4; ++mt) \
            af[mt] = *(const bf16x8*)&As[buf][(wm * 64 + mt * 16 + lr) * 32 + (lg ^ swl) * 8]; \
        _Pragma("unroll") \
        for (int nt = 0; nt < 2; ++nt) \
            bf[nt] = *(const bf16x8*)&Bs[buf][(wn * 32 + nt * 16 + lr) * 32 + (lg ^ swl) * 8]; \
        _Pragma("unroll") \
        for (int mt = 0; mt < 4; ++mt) \
            _Pragma("unroll") \
            for (int nt = 0; nt < 2; ++nt) \
                acc[mt][nt] = __builtin_amdgcn_mfma_f32_16x16x32_bf16(af[mt], bf[nt], acc[mt][nt], 0, 0, 0); \
    } while (0)

    STAGE(0, 0);
    __syncthreads();
    const int nk = K / 32;
    for (int t = 0; t < nk - 1; ++t) {
        STAGE((t + 1) & 1, (size_t)(t + 1) * 32);
        COMPUTE(t & 1);
        __syncthreads();
    }
    COMPUTE((nk - 1) & 1);

    const float* bias = ga.bias[z];
    float bv[2];
#pragma unroll
    for (int nt = 0; nt < 2; ++nt) bv[nt] = bias[n0 + wn * 32 + nt * 16 + lr];
    ushort* Cb = ga.Cb[z];
#pragma unroll
    for (int mt = 0; mt < 4; ++mt)
#pragma unroll
        for (int r4 = 0; r4 < 4; ++r4) {
            size_t m = m0 + wm * 64 + mt * 16 + lg * 4 + r4;
            ushort* crow = Cb + m * N + n0 + wn * 32 + lr;
#pragma unroll
            for (int nt = 0; nt < 2; ++nt)
                crow[nt * 16] = f2b(acc[mt][nt][r4] + bv[nt]);
        }
#undef STAGE
#undef COMPUTE
}

// ---------------------------------------------------------------------------
// Wo GEMM, BN=64 tile (unchanged R11)
// ---------------------------------------------------------------------------
__global__ __launch_bounds__(256) void gemm_wo(const ushort* __restrict__ A,
                                               const ushort* __restrict__ W,
                                               const float* __restrict__ bias,
                                               float* __restrict__ Cf) {
    const int M = BATCH * SEQ, N = HID, K = HID;
    __shared__ ushort As[2][128 * 32];
    __shared__ ushort Bs[2][64 * 32];
    const int tid = threadIdx.x;
    const int m0 = blockIdx.y * 128;
    const int n0 = blockIdx.x * 64;

    const int w  = tid >> 6;
    const int l  = tid & 63;
    const int lr = l & 15;
    const int lg = l >> 4;
    const int wm = w >> 1;
    const int wn = w & 1;

    const int sr = tid >> 2;
    const int sc = tid & 3;
    const int g  = sc ^ ((sr >> 1) & 3);
    const ushort* Ag0 = A + (size_t)(m0 + sr)      * K + g * 8;
    const ushort* Ag1 = A + (size_t)(m0 + sr + 64) * K + g * 8;
    const ushort* Wg0 = W + (size_t)(n0 + sr)      * K + g * 8;

    f32x4 acc[4][2];
#pragma unroll
    for (int mt = 0; mt < 4; ++mt)
#pragma unroll
        for (int nt = 0; nt < 2; ++nt) acc[mt][nt] = (f32x4){0.f, 0.f, 0.f, 0.f};

#define STAGE(buf, k0) do { \
        GL16(Ag0 + (k0), &As[buf][w * 512]); \
        GL16(Ag1 + (k0), &As[buf][2048 + w * 512]); \
        GL16(Wg0 + (k0), &Bs[buf][w * 512]); \
    } while (0)

    const int swl = (lr >> 1) & 3;
#define COMPUTE(buf) do { \
        bf16x8 af[4], bf[2]; \
        _Pragma("unroll") \
        for (int mt = 0; mt < 4; ++mt) \
            af[mt] = *(const bf16x8*)&As[buf][(wm * 64 + mt * 16 + lr) * 32 + (lg ^ swl) * 8]; \
        _Pragma("unroll") \
        for (int nt = 0; nt < 2; ++nt) \
            bf[nt] = *(const bf16x8*)&Bs[buf][(wn * 32 + nt * 16 + lr) * 32 + (lg ^ swl) * 8]; \
        _Pragma("unroll") \
        for (int mt = 0; mt < 4; ++mt) \
            _Pragma("unroll") \
            for (int nt = 0; nt < 2; ++nt) \
                acc[mt][nt] = __builtin_amdgcn_mfma_f32_16x16x32_bf16(af[mt], bf[nt], acc[mt][nt], 0, 0, 0); \
    } while (0)

    STAGE(0, 0);
    __syncthreads();
    const int nk = K / 32;
    for (int t = 0; t < nk - 1; ++t) {
        STAGE((t + 1) & 1, (size_t)(t + 1) * 32);
        COMPUTE(t & 1);
        __syncthreads();
    }
    COMPUTE((nk - 1) & 1);

    float bv[2];
#pragma unroll
    for (int nt = 0; nt < 2; ++nt) bv[nt] = bias[n0 + wn * 32 + nt * 16 + lr];
#pragma unroll
    for (int mt = 0; mt < 4; ++mt)
#pragma unroll
        for (int r4 = 0; r4 < 4; ++r4) {
            size_t m = m0 + wm * 64 + mt * 16 + lg * 4 + r4;
            float* crow = Cf + m * N + n0 + wn * 32 + lr;
#pragma unroll
            for (int nt = 0; nt < 2; ++nt)
                crow[nt * 16] = acc[mt][nt][r4] + bv[nt];
        }
#undef STAGE
#undef COMPUTE
}

// ---------------------------------------------------------------------------
// prep_kernel: qtab (MFMA) + V-transpose + tvT2 (padded [64][160]) + fm->u8
// ---------------------------------------------------------------------------
__global__ __launch_bounds__(256) void prep_kernel(const ushort* __restrict__ qb,
                                                   const float* __restrict__ table_k,
                                                   const ushort* __restrict__ vb,
                                                   const float* __restrict__ table_v,
                                                   const int* __restrict__ fmat,
                                                   ushort* __restrict__ qtab,
                                                   ushort* __restrict__ vT,
                                                   ushort* __restrict__ tvT2,
                                                   uchar* __restrict__ fm8) {
    __shared__ __align__(16) ushort shmem[144 * 72];
    const int wg  = blockIdx.x;
    const int tid = threadIdx.x;

    if (wg < 256) {
        const int h    = wg & 15;
        const int half = (wg >> 4) & 1;
        const int b    = wg >> 5;
        const int q0   = half * 256;
        ushort* tk = shmem;
        for (int i = tid; i < TAB * 8; i += 256) {
            int row = i >> 3, gr = i & 7;
            const float* src = table_k + row * HD + gr * 8;
            float4 a = *(const float4*)src;
            float4 c = *(const float4*)(src + 4);
            uint4 u;
            u.x = pk(a.x, a.y); u.y = pk(a.z, a.w);
            u.z = pk(c.x, c.y); u.w = pk(c.z, c.w);
            *(uint4*)&tk[row * 72 + gr * 8] = u;
        }
        __syncthreads();

        const int w  = tid >> 6;
        const int l  = tid & 63;
        const int lr = l & 15;
        const int lg = l >> 4;
        bf16x8 qf[4][2];
#pragma unroll
        for (int qt = 0; qt < 4; ++qt) {
            const ushort* qrow = qb + ((size_t)(b * SEQ) + q0 + w * 64 + qt * 16 + lr) * HID + h * HD;
            qf[qt][0] = *(const bf16x8*)(qrow + lg * 8);
            qf[qt][1] = *(const bf16x8*)(qrow + 32 + lg * 8);
        }
        ushort* outbase = qtab + ((size_t)(b * HEADS + h) * SEQ + q0 + w * 64) * QSTR;
#pragma unroll
        for (int mt = 0; mt < 9; ++mt) {
            bf16x8 tf0 = *(const bf16x8*)&tk[(mt * 16 + lr) * 72 + lg * 8];
            bf16x8 tf1 = *(const bf16x8*)&tk[(mt * 16 + lr) * 72 + 32 + lg * 8];
#pragma unroll
            for (int qt = 0; qt < 4; ++qt) {
                f32x4 acc = (f32x4){0.f, 0.f, 0.f, 0.f};
                acc = __builtin_amdgcn_mfma_f32_16x16x32_bf16(tf0, qf[qt][0], acc, 0, 0, 0);
                acc = __builtin_amdgcn_mfma_f32_16x16x32_bf16(tf1, qf[qt][1], acc, 0, 0, 0);
                ushort* orow = outbase + (size_t)(qt * 16 + lr) * QSTR;
                if (mt < 8) {
                    uint2 pu;
                    pu.x = pk(acc[0], acc[1]); pu.y = pk(acc[2], acc[3]);
                    *(uint2*)&orow[mt * 16 + lg * 4] = pu;
                } else if (lg == 0) {
                    orow[128] = f2b(acc[0]);
                }
            }
        }
    } else if (wg < 768) {
        const int vw = wg - 256;
        ushort* tile = shmem;
        const int b = vw >> 6, h = (vw >> 2) & 15, kc = vw & 3;
        const int k0 = kc * 128;
        {
            const int kr = tid >> 1, dc = (tid & 1) * 32;
            const ushort* src = vb + ((size_t)(b * SEQ) + k0 + kr) * HID + h * 64 + dc;
#pragma unroll
            for (int j = 0; j < 4; ++j) {
                uint4 u = *(const uint4*)(src + j * 8);
                *(uint4*)&tile[kr * 72 + dc + j * 8] = u;
            }
        }
        __syncthreads();
        {
            const int dr = tid >> 2, kc2 = (tid & 3) * 32;
            ushort* dst = vT + ((size_t)(b * 16 + h) * 64 + dr) * 512 + k0 + kc2;
#pragma unroll
            for (int j = 0; j < 4; ++j) {
                U16x8 o;
#pragma unroll
                for (int i = 0; i < 8; ++i)
                    o.s[i] = tile[(kc2 + j * 8 + i) * 72 + dr];
                *(uint4*)(dst + j * 8) = o.q;
            }
        }
    } else if (wg == 768) {
        for (int i = tid; i < 64 * 160; i += 256) {
            int d = i / 160;
            int c = i - d * 160;
            tvT2[i] = (c < TAB) ? f2b(table_v[(size_t)c * HD + d]) : (ushort)0;
        }
    } else {
        const size_t base = (size_t)(wg - 769) * 2048 + (size_t)tid * 8;
        int4 a = *(const int4*)(fmat + base);
        int4 c = *(const int4*)(fmat + base + 4);
        uint lo = (uint)a.x | ((uint)a.y << 8) | ((uint)a.z << 16) | ((uint)a.w << 24);
        uint hi = (uint)c.x | ((uint)c.y << 8) | ((uint)c.z << 16) | ((uint)c.w << 24);
        uint2 o; o.x = lo; o.y = hi;
        *(uint2*)(fm8 + base) = o;
    }
}

// ---------------------------------------------------------------------------
// qk_gemm: S[bh, q, k] = Q . K^T  (bf16 out).  (unchanged R13)
// ---------------------------------------------------------------------------
__global__ __launch_bounds__(256) void qk_gemm(const ushort* __restrict__ qb,
                                               const ushort* __restrict__ kb,
                                               ushort* __restrict__ S) {
    __shared__ ushort As[2][128 * 32];
    __shared__ ushort Bs[2][128 * 32];
    const int tid = threadIdx.x;
    const int m0 = blockIdx.x * 128;
    const int n0 = blockIdx.y * 128;
    const int bh = blockIdx.z;
    const int b = bh >> 4, h = bh & 15;
    const size_t rowQ = (size_t)b * SEQ;

    const int w  = tid >> 6;
    const int l  = tid & 63;
    const int lr = l & 15;
    const int lg = l >> 4;
    const int wm = w >> 1;
    const int wn = w & 1;

    const int sr = tid >> 2;
    const int sc = tid & 3;
    const int g  = sc ^ ((sr >> 1) & 3);
    const ushort* Ag0 = qb + (rowQ + m0 + sr)      * HID + h * HD + g * 8;
    const ushort* Ag1 = qb + (rowQ + m0 + sr + 64) * HID + h * HD + g * 8;
    const ushort* Wg0 = kb + (rowQ + n0 + sr)      * HID + h * HD + g * 8;
    const ushort* Wg1 = kb + (rowQ + n0 + sr + 64) * HID + h * HD + g * 8;

    GL16(Ag0,      &As[0][w * 512]); GL16(Ag1,      &As[0][2048 + w * 512]);
    GL16(Wg0,      &Bs[0][w * 512]); GL16(Wg1,      &Bs[0][2048 + w * 512]);
    GL16(Ag0 + 32, &As[1][w * 512]); GL16(Ag1 + 32, &As[1][2048 + w * 512]);
    GL16(Wg0 + 32, &Bs[1][w * 512]); GL16(Wg1 + 32, &Bs[1][2048 + w * 512]);

    f32x4 acc[4][4];
#pragma unroll
    for (int mt = 0; mt < 4; ++mt)
#pragma unroll
        for (int nt = 0; nt < 4; ++nt) acc[mt][nt] = (f32x4){0.f, 0.f, 0.f, 0.f};

    const int swl = (lr >> 1) & 3;
    __syncthreads();
#pragma unroll
    for (int buf = 0; buf < 2; ++buf) {
        bf16x8 af[4], bf[4];
#pragma unroll
        for (int mt = 0; mt < 4; ++mt)
            af[mt] = *(const bf16x8*)&As[buf][(wm * 64 + mt * 16 + lr) * 32 + (lg ^ swl) * 8];
#pragma unroll
        for (int nt = 0; nt < 4; ++nt)
            bf[nt] = *(const bf16x8*)&Bs[buf][(wn * 64 + nt * 16 + lr) * 32 + (lg ^ swl) * 8];
#pragma unroll
        for (int mt = 0; mt < 4; ++mt)
#pragma unroll
            for (int nt = 0; nt < 4; ++nt)
                acc[mt][nt] = __builtin_amdgcn_mfma_f32_16x16x32_bf16(af[mt], bf[nt], acc[mt][nt], 0, 0, 0);
    }

    ushort* Sb = S + (size_t)bh * SEQ * SEQ;
#pragma unroll
    for (int mt = 0; mt < 4; ++mt)
#pragma unroll
        for (int r4 = 0; r4 < 4; ++r4) {
            int m = m0 + wm * 64 + mt * 16 + lg * 4 + r4;
            ushort* srow = Sb + (size_t)m * SEQ + n0 + wn * 64 + lr;
#pragma unroll
            for (int nt = 0; nt < 4; ++nt)
                srow[nt * 16] = f2b(acc[mt][nt][r4]);
        }
}

// ---------------------------------------------------------------------------
// sm_kernel: per q-row softmax + gather + bin histogram (unchanged R13)
// ---------------------------------------------------------------------------
__global__ __launch_bounds__(256) void sm_kernel(ushort* __restrict__ S,
                                                 const ushort* __restrict__ qt,
                                                 const uchar* __restrict__ fm8,
                                                 ushort* __restrict__ binbuf) {
    constexpr float FIX = 65536.0f;
    constexpr float INV_FIX = 1.0f / 65536.0f;
    __shared__ uint binsL[4][160];
    const int tid = threadIdx.x;
    const int wv  = tid >> 6;
    const int l   = tid & 63;
    const int gr0 = blockIdx.x * 32 + wv * 8;

    for (int ri = 0; ri < 8; ++ri) {
        const int gr = gr0 + ri;
        const int q  = gr & 511;
        const int b  = gr >> 13;
        binsL[wv][l] = 0u;
        binsL[wv][l + 64] = 0u;
        if (l < 32) binsL[wv][l + 128] = 0u;

        U16x8 sv;
        sv.q = *(const uint4*)&S[((size_t)gr << 9) + l * 8];
        const uchar* fr = fm8 + ((((size_t)b << 9) + q) << 9) + l * 8;
        uint f0 = *(const uint*)fr;
        uint f1 = *(const uint*)(fr + 4);
        const ushort* qrow = qt + (size_t)gr * QSTR;

        int ts[8];
        ts[0] = f0 & 255; ts[1] = (f0 >> 8) & 255; ts[2] = (f0 >> 16) & 255; ts[3] = f0 >> 24;
        ts[4] = f1 & 255; ts[5] = (f1 >> 8) & 255; ts[6] = (f1 >> 16) & 255; ts[7] = f1 >> 24;

        float pr[8];
        float lsum = 0.f;
#pragma unroll
        for (int j = 0; j < 8; ++j) {
            float s = b2f(sv.s[j]);
            float gv = b2f(qrow[ts[j]]);
            pr[j] = __expf((s + gv) * 0.125f);
            lsum += pr[j];
        }
#pragma unroll
        for (int j = 0; j < 8; ++j)
            __hip_atomic_fetch_add(&binsL[wv][ts[j]], (uint)(pr[j] * FIX),
                                   __ATOMIC_RELAXED, __HIP_MEMORY_SCOPE_WORKGROUP);
#pragma unroll
        for (int off = 32; off >= 1; off >>= 1)
            lsum += __shfl_xor(lsum, off);
        const float invl = 1.f / lsum;

        U16x8 pv;
#pragma unroll
        for (int j = 0; j < 4; ++j)
            pv.u[j] = pk(pr[2 * j] * invl, pr[2 * j + 1] * invl);
        *(uint4*)&S[((size_t)gr << 9) + l * 8] = pv.q;

        asm volatile("s_waitcnt lgkmcnt(0)" ::: "memory");
        ushort* bb = binbuf + (size_t)gr * 160;
        const float sc = INV_FIX * invl;
        {
            int c = 2 * l;
            *(uint*)&bb[c] = pk((float)binsL[wv][c] * sc, (float)binsL[wv][c + 1] * sc);
        }
        if (l < 16) {
            int c = 128 + 2 * l;
            *(uint*)&bb[c] = pk((float)binsL[wv][c] * sc, (float)binsL[wv][c + 1] * sc);
        }
    }
}

// ---------------------------------------------------------------------------
// pv_gemm: O = P.V^T + bins.tvT2  (K = 512+160, unchanged R13)
// ---------------------------------------------------------------------------
__global__ __launch_bounds__(256) void pv_gemm(const ushort* __restrict__ P,
                                               const ushort* __restrict__ binbuf,
                                               const ushort* __restrict__ vT,
                                               const ushort* __restrict__ tvT2,
                                               ushort* __restrict__ x) {
    __shared__ ushort As[2][128 * 32];
    __shared__ ushort Bs[2][64 * 32];
    const int tid = threadIdx.x;
    const int m0 = blockIdx.x * 128;
    const int bh = blockIdx.y;
    const int b = bh >> 4, h = bh & 15;

    const int w  = tid >> 6;
    const int l  = tid & 63;
    const int lr = l & 15;
    const int lg = l >> 4;
    const int wm = w >> 1;
    const int wn = w & 1;

    const int sr = tid >> 2;
    const int sc = tid & 3;
    const int g  = sc ^ ((sr >> 1) & 3);
    const ushort* AgS0 = P + ((size_t)bh * SEQ + m0 + sr)      * 512 + g * 8;
    const ushort* AgS1 = P + ((size_t)bh * SEQ + m0 + sr + 64) * 512 + g * 8;
    const ushort* AgB0 = binbuf + ((size_t)bh * SEQ + m0 + sr)      * 160 + g * 8;
    const ushort* AgB1 = binbuf + ((size_t)bh * SEQ + m0 + sr + 64) * 160 + g * 8;
    const ushort* WgV  = vT + ((size_t)bh * 64 + sr) * 512 + g * 8;
    const ushort* WgT  = tvT2 + (size_t)sr * 160 + g * 8;

#define STAGE_C(buf, st) do { \
        const ushort* a0_ = (st) < 16 ? AgS0 + (st) * 32 : AgB0 + ((st) - 16) * 32; \
        const ushort* a1_ = (st) < 16 ? AgS1 + (st) * 32 : AgB1 + ((st) - 16) * 32; \
        const ushort* b0_ = (st) < 16 ? WgV  + (st) * 32 : WgT  + ((st) - 16) * 32; \
        GL16(a0_, &As[buf][w * 512]); \
        GL16(a1_, &As[buf][2048 + w * 512]); \
        GL16(b0_, &Bs[buf][w * 512]); \
    } while (0)

    f32x4 acc[4][2];
#pragma unroll
    for (int mt = 0; mt < 4; ++mt)
#pragma unroll
        for (int nt = 0; nt < 2; ++nt) acc[mt][nt] = (f32x4){0.f, 0.f, 0.f, 0.f};

    const int swl = (lr >> 1) & 3;
#define COMPUTE_C(buf) do { \
        bf16x8 af[4], bf[2]; \
        _Pragma("unroll") \
        for (int mt = 0; mt < 4; ++mt) \
            af[mt] = *(const bf16x8*)&As[buf][(wm * 64 + mt * 16 + lr) * 32 + (lg ^ swl) * 8]; \
        _Pragma("unroll") \
        for (int nt = 0; nt < 2; ++nt) \
            bf[nt] = *(const bf16x8*)&Bs[buf][(wn * 32 + nt * 16 + lr) * 32 + (lg ^ swl) * 8]; \
        _Pragma("unroll") \
        for (int mt = 0; mt < 4; ++mt) \
            _Pragma("unroll") \
            for (int nt = 0; nt < 2; ++nt) \
                acc[mt][nt] = __builtin_amdgcn_mfma_f32_16x16x32_bf16(af[mt], bf[nt], acc[mt][nt], 0, 0, 0); \
    } while (0)

    STAGE_C(0, 0);
    __syncthreads();
    const int nk = 21;
    for (int t = 0; t < nk - 1; ++t) {
        STAGE_C((t + 1) & 1, t + 1);
        COMPUTE_C(t & 1);
        __syncthreads();
    }
    COMPUTE_C((nk - 1) & 1);

#pragma unroll
    for (int mt = 0; mt < 4; ++mt)
#pragma unroll
        for (int r4 = 0; r4 < 4; ++r4) {
            int m = m0 + wm * 64 + mt * 16 + lg * 4 + r4;
            ushort* orow = x + ((size_t)(b * SEQ) + m) * HID + h * HD + wn * 32 + lr;
#pragma unroll
            for (int nt = 0; nt < 2; ++nt)
                orow[nt * 16] = f2b(acc[mt][nt][r4]);
        }
#undef STAGE_C
#undef COMPUTE_C
}

// ---------------------------------------------------------------------------
extern "C" void kernel_launch(void* const* d_in, const int* in_sizes, int n_in,
                              void* d_out, int out_size, void* d_ws, size_t ws_size,
                              hipStream_t stream) {
    const float* query = (const float*)d_in[0];
    const float* key   = (const float*)d_in[1];
    const float* value = (const float*)d_in[2];
    const int*   fmat  = (const int*)d_in[3];
    const float* Wq = (const float*)d_in[4];
    const float* bq = (const float*)d_in[5];
    const float* Wk = (const float*)d_in[6];
    const float* bk = (const float*)d_in[7];
    const float* Wv = (const float*)d_in[8];
    const float* bv = (const float*)d_in[9];
    const float* Wo = (const float*)d_in[10];
    const float* bo = (const float*)d_in[11];
    const float* table_k = (const float*)d_in[12];
    const float* table_v = (const float*)d_in[13];

    const size_t nBLD = (size_t)BATCH * SEQ * HID;   // 4,194,304
    const size_t nW   = (size_t)HID * HID;           // 1,048,576
    ushort* us = (ushort*)d_ws;
    ushort* qin16 = us;                 us += nBLD;   // reused as vT
    ushort* kin16 = us;                 us += nBLD;   // reused as tvT2
    ushort* vin16 = us;                 us += nBLD;
    ushort* wq16  = us;                 us += nW;
    ushort* wk16  = us;                 us += nW;
    ushort* wv16  = us;                 us += nW;
    ushort* wo16  = us;                 us += nW;
    ushort* qb16  = us;                 us += nBLD;
    ushort* kb16  = us;                 us += nBLD;
    ushort* vb16  = us;                 us += nBLD;
    ushort* qt16  = us;                 us += (size_t)BATCH * HEADS * SEQ * QSTR;
    ushort* xb16  = us;                 us += nBLD;
    uchar*  fm8   = (uchar*)us;         us += (size_t)BATCH * SEQ * SEQ / 2;
    ushort* Sbuf  = us;                 us += (size_t)BATCH * HEADS * SEQ * SEQ;
    ushort* binbf = us;                 us += (size_t)BATCH * HEADS * SEQ * 160;

    ConvArgs ca;
    ca.src[0] = query; ca.src[1] = key; ca.src[2] = value;
    ca.src[3] = Wq; ca.src[4] = Wk; ca.src[5] = Wv; ca.src[6] = Wo;
    ca.dst[0] = qin16; ca.dst[1] = kin16; ca.dst[2] = vin16;
    ca.dst[3] = wq16; ca.dst[4] = wk16; ca.dst[5] = wv16; ca.dst[6] = wo16;
    convert_bf16<<<dim3(8192), 256, 0, stream>>>(ca);

    const int M = BATCH * SEQ;  // 4096

    GemmArgs gq = {};
    gq.A[0] = qin16; gq.A[1] = kin16; gq.A[2] = vin16;
    gq.W[0] = wq16;  gq.W[1] = wk16;  gq.W[2] = wv16;
    gq.bias[0] = bq; gq.bias[1] = bk; gq.bias[2] = bv;
    gq.Cb[0] = qb16; gq.Cb[1] = kb16; gq.Cb[2] = vb16;
    gemm_qkv<<<dim3(1536), 256, 0, stream>>>(gq);

    ushort* vTbuf  = qin16;
    ushort* tvTbuf = kin16;

    prep_kernel<<<dim3(1793), 256, 0, stream>>>(qb16, table_k, vb16, table_v,
                                                fmat, qt16, vTbuf, tvTbuf, fm8);

    qk_gemm<<<dim3(4, 4, 128), 256, 0, stream>>>(qb16, kb16, Sbuf);
    sm_kernel<<<dim3(BATCH * HEADS * SEQ / 32), 256, 0, stream>>>(Sbuf, qt16, fm8, binbf);
    pv_gemm<<<dim3(4, 128), 256, 0, stream>>>(Sbuf, binbf, vTbuf, tvTbuf, xb16);

    gemm_wo<<<dim3(HID / 64, M / 128), 256, 0, stream>>>(xb16, wo16, bo, (float*)d_out);
}